// Round 12
// baseline (1887.628 us; speedup 1.0000x reference)
//
#include <hip/hip_runtime.h>

#define BATCH 64
#define SEQ   4096
#define ISZ   64
#define RSZ   128

typedef float  f32x4_t __attribute__((ext_vector_type(4)));
typedef float  f32x2_t __attribute__((ext_vector_type(2)));
typedef __fp16 f16x2_t __attribute__((ext_vector_type(2)));

__device__ __forceinline__ float fast_tanh(float x) {
    float e = __expf(2.0f * x);
    return 1.0f - 2.0f / (e + 1.0f);
}

__device__ __forceinline__ float dot2(f16x2_t a, f16x2_t b, float c) {
#if __has_builtin(__builtin_amdgcn_fdot2)
    return __builtin_amdgcn_fdot2(a, b, c, false);
#else
    return fmaf((float)a.x, (float)b.x, fmaf((float)a.y, (float)b.y, c));
#endif
}

// ---------------------------------------------------------------------------
// Kernel 1: projection. out[row][r] = tanh(sum_j x[row][j] * w_in[r][j])
// ---------------------------------------------------------------------------
__global__ __launch_bounds__(256) void proj_kernel(
        const float* __restrict__ x, const float* __restrict__ w_in,
        float* __restrict__ out) {
    __shared__ float wT[ISZ][RSZ];
    __shared__ float xs[32][ISZ];

    const int tid = threadIdx.x;

    for (int idx = tid; idx < RSZ * ISZ / 4; idx += 256) {
        const int r  = idx >> 4;
        const int j4 = (idx & 15) << 2;
        const float4 v = reinterpret_cast<const float4*>(w_in)[idx];
        wT[j4 + 0][r] = v.x; wT[j4 + 1][r] = v.y;
        wT[j4 + 2][r] = v.z; wT[j4 + 3][r] = v.w;
    }
    const long row0 = (long)blockIdx.x * 32;
    #pragma unroll
    for (int q = 0; q < 2; ++q) {
        const int idx = tid + q * 256;
        reinterpret_cast<float4*>(&xs[0][0])[idx] =
            reinterpret_cast<const float4*>(x + row0 * ISZ)[idx];
    }
    __syncthreads();

    const int rq = tid & 31;
    const int rp = tid >> 5;
    const int r0 = rq << 2;
    const int ra = rp << 2;

    float acc[4][4] = {};
    #pragma unroll
    for (int j4 = 0; j4 < ISZ; j4 += 4) {
        float4 xv[4];
        #pragma unroll
        for (int m = 0; m < 4; ++m)
            xv[m] = *reinterpret_cast<const float4*>(&xs[ra + m][j4]);
        #pragma unroll
        for (int k = 0; k < 4; ++k) {
            const float4 w = *reinterpret_cast<const float4*>(&wT[j4 + k][r0]);
            #pragma unroll
            for (int m = 0; m < 4; ++m) {
                const float xm = k == 0 ? xv[m].x : k == 1 ? xv[m].y
                               : k == 2 ? xv[m].z : xv[m].w;
                acc[m][0] += xm * w.x; acc[m][1] += xm * w.y;
                acc[m][2] += xm * w.z; acc[m][3] += xm * w.w;
            }
        }
    }
    #pragma unroll
    for (int m = 0; m < 4; ++m) {
        float4 o;
        o.x = fast_tanh(acc[m][0]); o.y = fast_tanh(acc[m][1]);
        o.z = fast_tanh(acc[m][2]); o.w = fast_tanh(acc[m][3]);
        *reinterpret_cast<float4*>(&out[(row0 + ra + m) * RSZ + r0]) = o;
    }
}

// ---------------------------------------------------------------------------
// Kernel 2: sequential scan — ONE WAVE PER BATCH, ZERO LDS, ZERO BARRIERS,
// ZERO manual waitcnt. h never touches memory: lane l owns the packed f16x2
// pair h{2l,2l+1} in ONE register; the all-to-all broadcast each step is
// 64 v_readlane ops (register->SGPR, independent, pipelined), each feeding
// v_dot2_f32_f16 as the legal single-SGPR operand. This removes round-10's
// per-step ds_write -> lgkmcnt(0) -> 16 uniform ds_read_b128 round trip,
// which counters showed dominated (VALUBusy 3.7% at 1029 cyc/step).
// Outputs accumulate in 8 f32x2 registers per 8-step phase, flushed at phase
// end as coalesced NT b64 stores (stores are always NEWER than any u load
// that gets waited on -> no store ever sits in front of a load in the vmcnt
// FIFO: round-4/6 lesson). u = 4-deep register prefetch (round-10 passing
// machinery, unchanged). W rows held as f16x2 (128 VGPRs).
// ---------------------------------------------------------------------------
__global__ __launch_bounds__(64, 1) void scan_kernel(
        const float* __restrict__ w_res, float* __restrict__ io) {
    const int lane = threadIdx.x;        // 0..63, one wave
    const int o0   = lane * 2;           // owned outputs / h pair {o0, o0+1}

    // W rows o0, o0+1 -> f16x2 in 128 VGPRs: wa[j] = {W[o0][2j], W[o0][2j+1]}
    f16x2_t wa[64], wb[64];
    #pragma unroll
    for (int k = 0; k < 128; k += 4) {
        const f32x4_t va = *reinterpret_cast<const f32x4_t*>(
            &w_res[o0 * RSZ + k]);
        const f32x4_t vb = *reinterpret_cast<const f32x4_t*>(
            &w_res[(o0 + 1) * RSZ + k]);
        wa[k / 2]     = __builtin_amdgcn_cvt_pkrtz(va.x, va.y);
        wa[k / 2 + 1] = __builtin_amdgcn_cvt_pkrtz(va.z, va.w);
        wb[k / 2]     = __builtin_amdgcn_cvt_pkrtz(vb.x, vb.y);
        wb[k / 2 + 1] = __builtin_amdgcn_cvt_pkrtz(vb.z, vb.w);
    }

    float* const out = io + (long)blockIdx.x * (SEQ * RSZ);

    // h_0 = 0, packed
    int hpacki = __builtin_bit_cast(int, __builtin_amdgcn_cvt_pkrtz(0.f, 0.f));
    f32x2_t hreg = {0.f, 0.f};

    // 4-deep u prefetch ring (coalesced f32x2 per lane), slots = rows 0..3
    f32x2_t u[4];
    #pragma unroll
    for (int s = 0; s < 4; ++s)
        u[s] = *reinterpret_cast<const f32x2_t*>(&out[s * RSZ + o0]);

    f32x2_t onh[8];                      // phase output accumulator (regs)

    // nh = 0.5*h + 0.5*tanh(v) = fma(0.5,h,0.5) - 1/(exp2(2*log2e*v)+1)
    #define ACT(HH, VV)                                                       \
        (fmaf(0.5f, (HH), 0.5f) -                                             \
         __builtin_amdgcn_rcpf(                                               \
             __builtin_amdgcn_exp2f((VV) * 2.885390082f) + 1.0f))

    #define STEP(S)                                                           \
    {                                                                         \
        int tp = t0 + (S) + 4;                                                \
        if (tp > SEQ - 1) tp = SEQ - 1;                                       \
        const f32x2_t uc = u[(S) & 3];                                        \
        u[(S) & 3] = *reinterpret_cast<const f32x2_t*>(&out[tp * RSZ + o0]);  \
        float a0a = 0.f, a0b = 0.f, a1a = 0.f, a1b = 0.f;                     \
        _Pragma("unroll")                                                     \
        for (int j = 0; j < 64; j += 2) {                                     \
            const f16x2_t h0 = __builtin_bit_cast(f16x2_t,                    \
                __builtin_amdgcn_readlane(hpacki, j));                        \
            const f16x2_t h1 = __builtin_bit_cast(f16x2_t,                    \
                __builtin_amdgcn_readlane(hpacki, j + 1));                    \
            a0a = dot2(h0, wa[j], a0a);                                       \
            a1a = dot2(h0, wb[j], a1a);                                       \
            a0b = dot2(h1, wa[j + 1], a0b);                                   \
            a1b = dot2(h1, wb[j + 1], a1b);                                   \
        }                                                                     \
        const float nh0 = ACT(hreg.x, uc.x + (a0a + a0b));                    \
        const float nh1 = ACT(hreg.y, uc.y + (a1a + a1b));                    \
        hreg.x = nh0; hreg.y = nh1;                                           \
        hpacki = __builtin_bit_cast(int,                                      \
                     __builtin_amdgcn_cvt_pkrtz(nh0, nh1));                   \
        onh[S].x = nh0; onh[S].y = nh1;                                       \
    }

    for (int t0 = 0; t0 < SEQ; t0 += 8) {
        STEP(0) STEP(1) STEP(2) STEP(3)
        STEP(4) STEP(5) STEP(6) STEP(7)
        // Flush the phase's 8 output rows: coalesced NT b64 stores
        // (issued after all this phase's u loads -> never force-drained).
        #pragma unroll
        for (int S = 0; S < 8; ++S)
            __builtin_nontemporal_store(onh[S], reinterpret_cast<f32x2_t*>(
                &out[(t0 + S) * RSZ + o0]));
    }
    #undef STEP
    #undef ACT
}

extern "C" void kernel_launch(void* const* d_in, const int* in_sizes, int n_in,
                              void* d_out, int out_size, void* d_ws, size_t ws_size,
                              hipStream_t stream) {
    const float* x     = (const float*)d_in[0];
    const float* w_in  = (const float*)d_in[1];
    const float* w_res = (const float*)d_in[2];
    float* out = (float*)d_out;

    proj_kernel<<<(BATCH * SEQ) / 32, 256, 0, stream>>>(x, w_in, out);
    scan_kernel<<<BATCH, 64, 0, stream>>>(w_res, out);
}

// Round 14
// 1229.478 us; speedup vs baseline: 1.5353x; 1.5353x over previous
//
#include <hip/hip_runtime.h>

#define BATCH 64
#define SEQ   4096
#define ISZ   64
#define RSZ   128

typedef float  f32x4_t __attribute__((ext_vector_type(4)));
typedef __fp16 f16x2_t __attribute__((ext_vector_type(2)));

__device__ __forceinline__ float fast_tanh(float x) {
    float e = __expf(2.0f * x);
    return 1.0f - 2.0f / (e + 1.0f);
}

__device__ __forceinline__ float dot2(f16x2_t a, f16x2_t b, float c) {
#if __has_builtin(__builtin_amdgcn_fdot2)
    return __builtin_amdgcn_fdot2(a, b, c, false);
#else
    return fmaf((float)a.x, (float)b.x, fmaf((float)a.y, (float)b.y, c));
#endif
}

// x + cross-lane(x) via DPP — pure VALU, no DS ops.
// 0xB1 = quad_perm[1,0,3,2] (xor1), 0x4E = quad_perm[2,3,0,1] (xor2),
// 0x141 = row_half_mirror (lane l <-> l^7 within each 8-lane half-row).
template <int CTRL>
__device__ __forceinline__ float dpp_add(float x) {
    int y = __builtin_amdgcn_update_dpp(0, __builtin_bit_cast(int, x),
                                        CTRL, 0xF, 0xF, true);
    return x + __builtin_bit_cast(float, y);
}

// ---------------------------------------------------------------------------
// Kernel 1: projection. out[row][r] = tanh(sum_j x[row][j] * w_in[r][j])
// ---------------------------------------------------------------------------
__global__ __launch_bounds__(256) void proj_kernel(
        const float* __restrict__ x, const float* __restrict__ w_in,
        float* __restrict__ out) {
    __shared__ float wT[ISZ][RSZ];
    __shared__ float xs[32][ISZ];

    const int tid = threadIdx.x;

    for (int idx = tid; idx < RSZ * ISZ / 4; idx += 256) {
        const int r  = idx >> 4;
        const int j4 = (idx & 15) << 2;
        const float4 v = reinterpret_cast<const float4*>(w_in)[idx];
        wT[j4 + 0][r] = v.x; wT[j4 + 1][r] = v.y;
        wT[j4 + 2][r] = v.z; wT[j4 + 3][r] = v.w;
    }
    const long row0 = (long)blockIdx.x * 32;
    #pragma unroll
    for (int q = 0; q < 2; ++q) {
        const int idx = tid + q * 256;
        reinterpret_cast<float4*>(&xs[0][0])[idx] =
            reinterpret_cast<const float4*>(x + row0 * ISZ)[idx];
    }
    __syncthreads();

    const int rq = tid & 31;
    const int rp = tid >> 5;
    const int r0 = rq << 2;
    const int ra = rp << 2;

    float acc[4][4] = {};
    #pragma unroll
    for (int j4 = 0; j4 < ISZ; j4 += 4) {
        float4 xv[4];
        #pragma unroll
        for (int m = 0; m < 4; ++m)
            xv[m] = *reinterpret_cast<const float4*>(&xs[ra + m][j4]);
        #pragma unroll
        for (int k = 0; k < 4; ++k) {
            const float4 w = *reinterpret_cast<const float4*>(&wT[j4 + k][r0]);
            #pragma unroll
            for (int m = 0; m < 4; ++m) {
                const float xm = k == 0 ? xv[m].x : k == 1 ? xv[m].y
                               : k == 2 ? xv[m].z : xv[m].w;
                acc[m][0] += xm * w.x; acc[m][1] += xm * w.y;
                acc[m][2] += xm * w.z; acc[m][3] += xm * w.w;
            }
        }
    }
    #pragma unroll
    for (int m = 0; m < 4; ++m) {
        float4 o;
        o.x = fast_tanh(acc[m][0]); o.y = fast_tanh(acc[m][1]);
        o.z = fast_tanh(acc[m][2]); o.w = fast_tanh(acc[m][3]);
        *reinterpret_cast<float4*>(&out[(row0 + ra + m) * RSZ + r0]) = o;
    }
}

// ---------------------------------------------------------------------------
// Kernel 2: sequential scan. Round-6 structure (1460 us proven: one block per
// batch, 4 waves; lane (grp = lane>>3, sl = lane&7) does rows r0..r0+3 x
// k-slice [16sl,16sl+16); 12-DPP reduce; 4 redundant ACTs; stage ring + NT
// flush; 4-deep u prefetch; raw s_barrier + lgkmcnt(0)-only wait) with two
// diet changes, BOTH carried through float-typed LDS accesses only (rounds
// 11/13 failed identically — and only they — when LDS h went through
// unsigned-int ext-vector loads/stores; all passing rounds used float/f16
// types, so packed contents ride inside floats via bit_cast):
//  (a) h in LDS as packed f16 pairs stored in a FLOAT array: per-lane h read
//      4 -> 2 ds_read_b128 (float4), h write one float2 (ds_write_b64).
//  (b) dot via v_dot2_f32_f16 (proven on gfx950 in rounds 10/12):
//      64 f32 FMA -> 32 dot2; W pre-packed f16x2 (32 VGPR).
// Bank math: reads are 8 distinct b128 addresses per wave, 2-way aliased
// (free, m136), broadcast across grp. f16 precision validated r10/12.
// ---------------------------------------------------------------------------
__global__ __launch_bounds__(256) void scan_kernel(
        const float* __restrict__ w_res, float* __restrict__ io) {
    __shared__ float hq[2][80];          // packed f16x2-in-float, dbuf (64 used)
    __shared__ float stage[16 * 128];    // 8 KB ring, slot = t & 15

    const int tid  = threadIdx.x;
    const int lane = tid & 63;
    const int wave = tid >> 6;
    const int grp  = lane >> 3;          // 8 output groups of 4
    const int sl   = lane & 7;           // 8 k-slices of 16
    const int r0   = wave * 32 + grp * 4;
    const int kb   = sl * 16;

    // W_res rows r0..r0+3, cols kb..kb+15 -> f16x2 (32 VGPRs)
    f16x2_t w2[4][8];
    #pragma unroll
    for (int rr = 0; rr < 4; ++rr) {
        #pragma unroll
        for (int kk = 0; kk < 16; kk += 4) {
            const f32x4_t v = *reinterpret_cast<const f32x4_t*>(
                &w_res[(r0 + rr) * RSZ + kb + kk]);
            w2[rr][kk / 2]     = __builtin_amdgcn_cvt_pkrtz(v.x, v.y);
            w2[rr][kk / 2 + 1] = __builtin_amdgcn_cvt_pkrtz(v.z, v.w);
        }
    }

    for (int i = tid; i < 2 * 80; i += 256) (&hq[0][0])[i] = 0.0f;

    float* const out = io + (long)blockIdx.x * (SEQ * RSZ);
    const int hrd = 8 * sl;              // float index of k-slice base
    const int hwr = 16 * wave + 2 * grp; // float index of own packed pair

    // 4-deep u prefetch ring (float4 per lane at r0 — verbatim round 6)
    float4 u[4];
    #pragma unroll
    for (int s = 0; s < 4; ++s)
        u[s] = *reinterpret_cast<const float4*>(&out[s * RSZ + r0]);
    float4 hreg = {0.f, 0.f, 0.f, 0.f};
    __syncthreads();

    // nh = 0.5*h + 0.5*tanh(v) = fma(0.5,h,0.5) - 1/(exp2(2*log2e*v)+1)
    #define ACT(HH, VV)                                                       \
        (fmaf(0.5f, (HH), 0.5f) -                                             \
         __builtin_amdgcn_rcpf(                                               \
             __builtin_amdgcn_exp2f((VV) * 2.885390082f) + 1.0f))

    #define STEP(S)                                                           \
    {                                                                         \
        int tp = t0 + (S) + 4;                                                \
        if (tp > SEQ - 1) tp = SEQ - 1;                                       \
        const float4 uc = u[(S) & 3];                                         \
        u[(S) & 3] = *reinterpret_cast<const float4*>(&out[tp * RSZ + r0]);   \
        const float4 p0 = *reinterpret_cast<const float4*>(                   \
            &hq[(S) & 1][hrd]);                                               \
        const float4 p1 = *reinterpret_cast<const float4*>(                   \
            &hq[(S) & 1][hrd + 4]);                                           \
        f16x2_t hv[8];                                                        \
        hv[0] = __builtin_bit_cast(f16x2_t, p0.x);                            \
        hv[1] = __builtin_bit_cast(f16x2_t, p0.y);                            \
        hv[2] = __builtin_bit_cast(f16x2_t, p0.z);                            \
        hv[3] = __builtin_bit_cast(f16x2_t, p0.w);                            \
        hv[4] = __builtin_bit_cast(f16x2_t, p1.x);                            \
        hv[5] = __builtin_bit_cast(f16x2_t, p1.y);                            \
        hv[6] = __builtin_bit_cast(f16x2_t, p1.z);                            \
        hv[7] = __builtin_bit_cast(f16x2_t, p1.w);                            \
        float a0 = 0.f, a1 = 0.f, a2 = 0.f, a3 = 0.f;                         \
        _Pragma("unroll")                                                     \
        for (int j = 0; j < 8; ++j) {                                         \
            a0 = dot2(hv[j], w2[0][j], a0);                                   \
            a1 = dot2(hv[j], w2[1][j], a1);                                   \
            a2 = dot2(hv[j], w2[2][j], a2);                                   \
            a3 = dot2(hv[j], w2[3][j], a3);                                   \
        }                                                                     \
        a0 = dpp_add<0xB1>(a0);  a1 = dpp_add<0xB1>(a1);                      \
        a2 = dpp_add<0xB1>(a2);  a3 = dpp_add<0xB1>(a3);                      \
        a0 = dpp_add<0x4E>(a0);  a1 = dpp_add<0x4E>(a1);                      \
        a2 = dpp_add<0x4E>(a2);  a3 = dpp_add<0x4E>(a3);                      \
        a0 = dpp_add<0x141>(a0); a1 = dpp_add<0x141>(a1);                     \
        a2 = dpp_add<0x141>(a2); a3 = dpp_add<0x141>(a3);                     \
        float4 nh;                                                            \
        nh.x = ACT(hreg.x, uc.x + a0);                                        \
        nh.y = ACT(hreg.y, uc.y + a1);                                        \
        nh.z = ACT(hreg.z, uc.z + a2);                                        \
        nh.w = ACT(hreg.w, uc.w + a3);                                        \
        hreg = nh;                                                            \
        if (sl == 0) {                                                        \
            float2 pv;                                                        \
            pv.x = __builtin_bit_cast(float,                                  \
                       __builtin_amdgcn_cvt_pkrtz(nh.x, nh.y));               \
            pv.y = __builtin_bit_cast(float,                                  \
                       __builtin_amdgcn_cvt_pkrtz(nh.z, nh.w));               \
            *reinterpret_cast<float2*>(&hq[1 - ((S) & 1)][hwr]) = pv;         \
        } else if (sl == 1) {                                                 \
            *reinterpret_cast<float4*>(                                       \
                &stage[((t0 & 8) + (S)) * 128 + r0]) = nh;                    \
        }                                                                     \
        asm volatile("s_waitcnt lgkmcnt(0)" ::: "memory");                    \
        __builtin_amdgcn_s_barrier();                                         \
        asm volatile("" ::: "memory");                                        \
    }

    const int fstep = tid >> 5;          // 0..7: which step of the half
    const int felem = (tid & 31) * 4;    // 0..124: element quad

    for (int t0 = 0; t0 < SEQ; t0 += 8) {
        STEP(0) STEP(1) STEP(2) STEP(3)
        STEP(4) STEP(5) STEP(6) STEP(7)
        // Flush this iteration's 8 staged steps: coalesced LDS read + NT store
        const f32x4_t v = *reinterpret_cast<const f32x4_t*>(
            &stage[((t0 & 8) + fstep) * 128 + felem]);
        __builtin_nontemporal_store(v,
            reinterpret_cast<f32x4_t*>(&out[(t0 + fstep) * RSZ + felem]));
    }
    #undef STEP
    #undef ACT
}

extern "C" void kernel_launch(void* const* d_in, const int* in_sizes, int n_in,
                              void* d_out, int out_size, void* d_ws, size_t ws_size,
                              hipStream_t stream) {
    const float* x     = (const float*)d_in[0];
    const float* w_in  = (const float*)d_in[1];
    const float* w_res = (const float*)d_in[2];
    float* out = (float*)d_out;

    proj_kernel<<<(BATCH * SEQ) / 32, 256, 0, stream>>>(x, w_in, out);
    scan_kernel<<<BATCH, 256, 0, stream>>>(w_res, out);
}